// Round 6
// baseline (95.575 us; speedup 1.0000x reference)
//
#include <hip/hip_runtime.h>

#define HOP 256
#define CUT 513
#define T_FRAMES 1021
#define N_SAMPLES 262144
#define BATCH 16
#define NGRP_PER_B 256                  // groups of 4 frames (2 packed FFTs)
#define NWG (BATCH * NGRP_PER_B)        // 4096, divisible by 8 XCDs

// XOR swizzle for double2 LDS arrays (slot = 16B granule, 8 per row)
__device__ __forceinline__ int pswz(int i) { return i ^ ((i >> 3) & 7); }
// 8-bit base-4 digit reversal (involution on [0,256))
__device__ __forceinline__ int drev8(int t) {
    return ((t & 3) << 6) | (((t >> 2) & 3) << 4) | (((t >> 4) & 3) << 2) | ((t >> 6) & 3);
}

// radix-4 DIF butterfly with twiddles W^e, W^2e, W^3e applied to o1,o2,o3
__device__ __forceinline__ void bfly(double2 A, double2 B, double2 C, double2 D,
    double c1, double s1, double c2, double s2, double c3, double s3,
    double2& o0, double2& o1, double2& o2, double2& o3)
{
    double t0r = A.x + C.x,  t0i = A.y + C.y;
    double t1r = A.x - C.x,  t1i = A.y - C.y;
    double t2r = B.x + D.x,  t2i = B.y + D.y;
    double t3r = B.x - D.x,  t3i = B.y - D.y;
    double y0r = t0r + t2r, y0i = t0i + t2i;
    double y2r = t0r - t2r, y2i = t0i - t2i;
    double y1r = t1r + t3i, y1i = t1i - t3r;   // (t1 - i*t3)
    double y3r = t1r - t3i, y3i = t1i + t3r;   // (t1 + i*t3)
    o0 = make_double2(y0r, y0i);
    o1 = make_double2(y1r * c1 + y1i * s1, y1i * c1 - y1r * s1);
    o2 = make_double2(y2r * c2 + y2i * s2, y2i * c2 - y2r * s2);
    o3 = make_double2(y3r * c3 + y3i * s3, y3i * c3 - y3r * s3);
}

// unpack packed-real-pair spectrum at bins r (y0,w3) and 256+r (y1,w2),
// write mag/phase for columns t0col (frame A) and t0col+1 (frame B)
__device__ __forceinline__ void emit2(float* __restrict__ omag, float* __restrict__ oph,
    int r, int t0col, bool hasB, double2 y0, double2 y1, double2 w3, double2 w2)
{
    {
        float arf = (float)(0.5 * (y0.x + w3.x));
        float aif = (float)(0.5 * (y0.y - w3.y));
        size_t g = (size_t)r * T_FRAMES + (size_t)t0col;
        omag[g] = sqrtf(arf * arf + aif * aif);
        oph[g]  = atan2f(aif, arf);
        if (hasB) {
            float brf = (float)(0.5 * (y0.y + w3.y));
            float bif = (float)(0.5 * (w3.x - y0.x));
            omag[g + 1] = sqrtf(brf * brf + bif * bif);
            oph[g + 1]  = atan2f(bif, brf);
        }
    }
    {
        float arf = (float)(0.5 * (y1.x + w2.x));
        float aif = (float)(0.5 * (y1.y - w2.y));
        size_t g = (size_t)(256 + r) * T_FRAMES + (size_t)t0col;
        omag[g] = sqrtf(arf * arf + aif * aif);
        oph[g]  = atan2f(aif, arf);
        if (hasB) {
            float brf = (float)(0.5 * (y1.y + w2.y));
            float bif = (float)(0.5 * (w2.x - y1.x));
            omag[g + 1] = sqrtf(brf * brf + bif * bif);
            oph[g + 1]  = atan2f(bif, brf);
        }
    }
}

__global__ __launch_bounds__(256, 4) void stft_fft_kernel(
    const float* __restrict__ x,
    const float* __restrict__ basis,
    float* __restrict__ out)
{
    __shared__ double2 z[2048];      // two packed FFTs, XOR-swizzled per 1024
    __shared__ double2 tw[256];      // (cos,sin) of 2*pi*j/1024, XOR-swizzled
    __shared__ float red[4][4];      // [wave][frame] imag-Nyquist partials

    const int tid = threadIdx.x;
    // XCD-chunked bijective swizzle: 512 consecutive groups per XCD
    const int wid = (blockIdx.x & 7) * (NWG / 8) + (blockIdx.x >> 3);
    const int b   = wid >> 8;
    const int g   = wid & 255;
    const int t0  = 4 * g;
    const bool hasF1 = (t0 + 1 < T_FRAMES);   // block-uniform
    const bool hasF2 = (t0 + 2 < T_FRAMES);
    const bool hasF3 = (t0 + 3 < T_FRAMES);

    // ---- twiddle build: angle(j) = a*(pi/8) + 2*pi*m/1024, j = 64a + m.
    // Poly on x <= 0.3866 (trunc err ~2e-14) + exact rotation constants. ----
    {
        const int m = tid & 63, a = tid >> 6;
        double xx = (6.2831853071795864769252867665590057684 / 1024.0) * (double)m;
        double x2 = xx * xx;
        double cc = 1.0 + x2 * (-0.5 + x2 * (1.0/24.0 + x2 * (-1.0/720.0
                   + x2 * (1.0/40320.0 + x2 * (-1.0/3628800.0)))));
        double ss = xx * (1.0 + x2 * (-1.0/6.0 + x2 * (1.0/120.0 + x2 * (-1.0/5040.0
                   + x2 * (1.0/362880.0 + x2 * (-1.0/39916800.0))))));
        double ca = (a == 0) ? 1.0
                  : (a == 1) ? 0.92387953251128675612818318939679
                  : (a == 2) ? 0.70710678118654752440084436210485
                             : 0.38268343236508977172845998403040;
        double sa = (a == 0) ? 0.0
                  : (a == 1) ? 0.38268343236508977172845998403040
                  : (a == 2) ? 0.70710678118654752440084436210485
                             : 0.92387953251128675612818318939679;
        tw[pswz(tid)] = make_double2(cc * ca - ss * sa, ss * ca + cc * sa);
    }

    const float* xb    = x + (size_t)b * N_SAMPLES;
    const float* wrow  = basis;                         // row 0 == Hann window
    const float* r1025 = basis + (size_t)1025 * 1024;   // imag Nyquist row (tiny)
    const int s0 = t0 * HOP;

    // 7 x 256 contiguous samples cover the 4 overlapping frames
    float v[7], wv[4], cny[4];
    #pragma unroll
    for (int j = 0; j < 7; ++j) {
        int idx = s0 + tid + 256 * j;
        v[j] = (idx < N_SAMPLES) ? xb[idx] : 0.0f;
    }
    #pragma unroll
    for (int j = 0; j < 4; ++j) {
        wv[j]  = wrow[tid + 256 * j];
        cny[j] = r1025[tid + 256 * j];
    }

    // pack frames (f0,f1) -> FFT1, (f2,f3) -> FFT2; fp32 imag-Nyquist dots
    float I0 = 0.f, I1 = 0.f, I2 = 0.f, I3 = 0.f;
    #pragma unroll
    for (int j = 0; j < 4; ++j) {
        int n = tid + 256 * j;
        double w = (double)wv[j];
        z[pswz(n)]        = make_double2(w * (double)v[j],     w * (double)v[j + 1]);
        z[1024 + pswz(n)] = make_double2(w * (double)v[j + 2], w * (double)v[j + 3]);
        I0 += cny[j] * v[j];     I1 += cny[j] * v[j + 1];
        I2 += cny[j] * v[j + 2]; I3 += cny[j] * v[j + 3];
    }
    #pragma unroll
    for (int off = 32; off > 0; off >>= 1) {
        I0 += __shfl_down(I0, off); I1 += __shfl_down(I1, off);
        I2 += __shfl_down(I2, off); I3 += __shfl_down(I3, off);
    }
    if ((tid & 63) == 0) {
        int w4 = tid >> 6;
        red[w4][0] = I0; red[w4][1] = I1; red[w4][2] = I2; red[w4][3] = I3;
    }
    __syncthreads();

    // ---- 4 radix-4 DIF stages, two FFTs interleaved through LDS ----
    #pragma unroll
    for (int s = 0; s < 4; ++s) {
        const int m4 = 1024 >> (2 * s);
        const int q  = m4 >> 2;
        const int n  = tid & (q - 1);
        const int base = (tid >> (8 - 2 * s)) * m4 + n;
        const int e  = n << (2 * s);          // always < 256
        const int i0 = pswz(base),         i1 = pswz(base + q);
        const int i2 = pswz(base + 2 * q), i3 = pswz(base + 3 * q);
        double2 A1 = z[i0],        B1 = z[i1],        C1 = z[i2],        D1 = z[i3];
        double2 A2 = z[1024 + i0], B2 = z[1024 + i1], C2 = z[1024 + i2], D2 = z[1024 + i3];
        double2 T1 = tw[pswz(e)];
        double c1 = T1.x, s1 = T1.y;
        int e2 = 2 * e;  int r2 = e2 & 255;
        double2 T2 = tw[pswz(r2)];
        double c2 = (e2 < 256) ? T2.x : -T2.y;
        double s2 = (e2 < 256) ? T2.y :  T2.x;
        int e3 = 3 * e;  int r3 = e3 & 255;  int q3 = e3 >> 8;
        double2 T3 = tw[pswz(r3)];
        double c3 = (q3 == 0) ? T3.x : ((q3 == 1) ? -T3.y : -T3.x);
        double s3 = (q3 == 0) ? T3.y : ((q3 == 1) ?  T3.x : -T3.y);
        double2 o0, o1, o2, o3;
        bfly(A1, B1, C1, D1, c1, s1, c2, s2, c3, s3, o0, o1, o2, o3);
        z[i0] = o0; z[i1] = o1; z[i2] = o2; z[i3] = o3;
        bfly(A2, B2, C2, D2, c1, s1, c2, s2, c3, s3, o0, o1, o2, o3);
        z[1024 + i0] = o0; z[1024 + i1] = o1; z[1024 + i2] = o2; z[1024 + i3] = o3;
        __syncthreads();
    }

    // ---- stage 4 (q=1, e=0): thread-private reads, results stay in regs.
    // Position 4t+c holds bin 256c + drev8(t). ----
    const int j0 = pswz(4 * tid + 0), j1 = pswz(4 * tid + 1);
    const int j2 = pswz(4 * tid + 2), j3 = pswz(4 * tid + 3);
    double2 y0a, y1a, y2a, y3a, y0b, y1b, y2b, y3b;
    bfly(z[j0], z[j1], z[j2], z[j3], 1,0, 1,0, 1,0, y0a, y1a, y2a, y3a);
    bfly(z[1024 + j0], z[1024 + j1], z[1024 + j2], z[1024 + j3], 1,0, 1,0, 1,0,
         y0b, y1b, y2b, y3b);

    // exchange: write own 4 back in place (thread-private slots, no hazard)
    z[j0] = y0a; z[j1] = y1a; z[j2] = y2a; z[j3] = y3a;
    z[1024 + j0] = y0b; z[1024 + j1] = y1b; z[1024 + j2] = y2b; z[1024 + j3] = y3b;
    __syncthreads();

    // conjugate partner: tp = drev8((256 - r) & 255), r = drev8(tid)
    const int r  = drev8(tid);
    const int rm = (256 - r) & 255;
    const int tp = drev8(rm);
    const int p3 = pswz(4 * tp + 3), p2 = pswz(4 * tp + 2);
    double2 w3a = z[p3], w2a = z[p2];            // bins 1024-r, 768-r (r>0)
    double2 w3b = z[1024 + p3], w2b = z[1024 + p2];
    if (tid == 0) { w3a = y0a; w2a = y3a; w3b = y0b; w2b = y3b; }  // r=0 mirrors

    float* omag = out + (size_t)b * CUT * T_FRAMES;
    float* oph  = omag + (size_t)BATCH * CUT * T_FRAMES;

    emit2(omag, oph, r, t0,     hasF1, y0a, y1a, w3a, w2a);
    if (hasF2)
        emit2(omag, oph, r, t0 + 2, hasF3, y0b, y1b, w3b, w2b);

    // bin 512: real from FFT (thread 0's y2), imag from the explicit dots
    if (tid == 0) {
        float iA = red[0][0] + red[1][0] + red[2][0] + red[3][0];
        float iB = red[0][1] + red[1][1] + red[2][1] + red[3][1];
        float iC = red[0][2] + red[1][2] + red[2][2] + red[3][2];
        float iD = red[0][3] + red[1][3] + red[2][3] + red[3][3];
        size_t gg = (size_t)512 * T_FRAMES + (size_t)t0;
        {
            float rf = (float)y2a.x;
            omag[gg] = sqrtf(rf * rf + iA * iA);
            oph[gg]  = atan2f(iA, rf);
        }
        if (hasF1) {
            float rf = (float)y2a.y;
            omag[gg + 1] = sqrtf(rf * rf + iB * iB);
            oph[gg + 1]  = atan2f(iB, rf);
        }
        if (hasF2) {
            float rf = (float)y2b.x;
            omag[gg + 2] = sqrtf(rf * rf + iC * iC);
            oph[gg + 2]  = atan2f(iC, rf);
        }
        if (hasF3) {
            float rf = (float)y2b.y;
            omag[gg + 3] = sqrtf(rf * rf + iD * iD);
            oph[gg + 3]  = atan2f(iD, rf);
        }
    }
}

extern "C" void kernel_launch(void* const* d_in, const int* in_sizes, int n_in,
                              void* d_out, int out_size, void* d_ws, size_t ws_size,
                              hipStream_t stream) {
    (void)in_sizes; (void)n_in; (void)d_ws; (void)ws_size; (void)out_size;
    const float* x     = (const float*)d_in[0];
    const float* basis = (const float*)d_in[1];
    float* out = (float*)d_out;
    dim3 grid(NWG);     // 4096
    dim3 block(256);
    stft_fft_kernel<<<grid, block, 0, stream>>>(x, basis, out);
}